// Round 1
// baseline (362.640 us; speedup 1.0000x reference)
//
#include <hip/hip_runtime.h>

#define H 1024
#define E 64
#define TOPK 8
#define BT 64          // tokens per block (pass A)
#define THETA 1e-4f    // logit-gap risk threshold for fp64 fixup

// ---------------- wave-wide helpers (wave = 64 lanes) ----------------
__device__ __forceinline__ float wave_max_f(float v) {
    #pragma unroll
    for (int off = 32; off > 0; off >>= 1) v = fmaxf(v, __shfl_xor(v, off, 64));
    return v;
}
__device__ __forceinline__ float wave_sum_f(float v) {
    #pragma unroll
    for (int off = 32; off > 0; off >>= 1) v += __shfl_xor(v, off, 64);
    return v;
}
__device__ __forceinline__ unsigned long long wave_max_u64(unsigned long long v) {
    #pragma unroll
    for (int off = 32; off > 0; off >>= 1) {
        unsigned long long o = __shfl_xor(v, off, 64);
        v = (o > v) ? o : v;
    }
    return v;
}

// =====================================================================
// Pass A: fp32 logits GEMM (64 tokens x 64 experts per block), softmax,
// top-8 w/ renorm, aux-loss partials, risky-token flagging.
// LDS: h[64][128] + w[64][128] fp32, XOR-swizzled (k-quad ^ (row>>2)&7)
// so staging stores and 4x4 outer-product b128 reads are conflict-free.
// =====================================================================
__global__ __launch_bounds__(256, 2)
void gate_main(const float* __restrict__ hs, const float* __restrict__ wt,
               float* __restrict__ out, float* __restrict__ pi_ws,
               float* __restrict__ ce_ws, unsigned int* __restrict__ risk_cnt,
               unsigned int* __restrict__ risk_list, unsigned int risk_cap,
               int n_tokens) {
    __shared__ float smem[16384];                 // 64 KB: h4 | w4, later S + hist
    float4* h4 = (float4*)smem;                   // [64 rows][32 float4]
    float4* w4 = (float4*)(smem + 8192);          // [64 rows][32 float4]

    const int t = threadIdx.x;
    const int tok_base = blockIdx.x * BT;
    const int tgi = t & 15;                       // token group 0..15 (4 tokens each)
    const int eg  = t >> 4;                       // expert group 0..15 (4 experts each)
    const int swz_h = tgi & 7;                    // row>>2 for rows tgi*4..+3
    const int swz_w = eg & 7;

    const float4* hs4 = (const float4*)hs;
    const float4* wt4 = (const float4*)wt;

    float acc[4][4];
    #pragma unroll
    for (int j = 0; j < 4; ++j)
        #pragma unroll
        for (int i = 0; i < 4; ++i) acc[j][i] = 0.f;

    for (int c = 0; c < 8; ++c) {                 // 8 K-chunks of 128
        // stage h and w chunk: 64 rows x 32 float4 each, coalesced global reads
        #pragma unroll
        for (int i = 0; i < 8; ++i) {
            int row = i * 8 + (t >> 5);           // 0..63
            int kq  = t & 31;                     // float4 index within chunk row
            int sw  = (row >> 2) & 7;
            h4[row * 32 + (kq ^ sw)] = hs4[(size_t)(tok_base + row) * 256 + c * 32 + kq];
            w4[row * 32 + (kq ^ sw)] = wt4[(size_t)row * 256 + c * 32 + kq];
        }
        __syncthreads();
        #pragma unroll 8
        for (int kq = 0; kq < 32; ++kq) {         // 4 logical k per iter
            const int ph = kq ^ swz_h;
            const int pw = kq ^ swz_w;
            float4 hv[4], wv[4];
            #pragma unroll
            for (int j = 0; j < 4; ++j) hv[j] = h4[(tgi * 4 + j) * 32 + ph];
            #pragma unroll
            for (int i = 0; i < 4; ++i) wv[i] = w4[(eg * 4 + i) * 32 + pw];
            #pragma unroll
            for (int j = 0; j < 4; ++j)
                #pragma unroll
                for (int i = 0; i < 4; ++i) {
                    acc[j][i] = fmaf(hv[j].x, wv[i].x, acc[j][i]);
                    acc[j][i] = fmaf(hv[j].y, wv[i].y, acc[j][i]);
                    acc[j][i] = fmaf(hv[j].z, wv[i].z, acc[j][i]);
                    acc[j][i] = fmaf(hv[j].w, wv[i].w, acc[j][i]);
                }
        }
        __syncthreads();
    }

    // ---- scatter logits to S[64][65] (stride 65 -> conflict-friendly) ----
    #pragma unroll
    for (int j = 0; j < 4; ++j)
        #pragma unroll
        for (int i = 0; i < 4; ++i)
            smem[(tgi * 4 + j) * 65 + (eg * 4 + i)] = acc[j][i];
    if (t < 64) smem[4608 + t] = 0.f;             // expert histogram
    __syncthreads();

    // ---- per-token softmax + top-8: one wave handles 16 tokens ----
    const int wave = t >> 6, lane = t & 63;
    float pi_acc = 0.f;
    for (int tt = 0; tt < 16; ++tt) {
        const int tl = wave * 16 + tt;
        const int tok_g = tok_base + tl;
        const float s = smem[tl * 65 + lane];     // logit for expert `lane`
        const float m = wave_max_f(s);
        const float p = __expf(s - m);
        const float sum = wave_sum_f(p);
        pi_acc += p / sum;                        // full-softmax score (for pi)

        // order-preserving u64 key; low bits prefer smaller index on ties
        unsigned int b = __float_as_uint(s);
        unsigned int k32 = (b & 0x80000000u) ? ~b : (b | 0x80000000u);
        unsigned long long kw =
            ((unsigned long long)k32 << 32) | (unsigned long long)(63 - lane);

        float psum = 0.f, prevl = 0.f, mingap = 1e30f, mypv = 0.f;
        int myidx = 0;
        #pragma unroll
        for (int r = 0; r < 8; ++r) {
            unsigned long long kmax = wave_max_u64(kw);
            int widx = 63 - (int)(kmax & 63ull);
            float pwin = __shfl(p, widx, 64);
            float lwin = __shfl(s, widx, 64);
            psum += pwin;
            if (lane == r) { myidx = widx; mypv = pwin; }
            if (r > 0) mingap = fminf(mingap, prevl - lwin);
            prevl = lwin;
            if (lane == widx) kw = (unsigned long long)(63 - lane); // kill winner
        }
        {   // 9th max for the inclusion-boundary gap
            unsigned long long kmax = wave_max_u64(kw);
            int widx = 63 - (int)(kmax & 63ull);
            float lwin = __shfl(s, widx, 64);
            mingap = fminf(mingap, prevl - lwin);
        }
        const float wsum = psum + 1e-20f;
        if (lane < 8) {
            out[(size_t)tok_g * 8 + lane] = (float)myidx;
            out[(size_t)n_tokens * 8 + (size_t)tok_g * 8 + lane] = mypv / wsum;
            atomicAdd(&smem[4608 + myidx], 1.0f); // 8 distinct experts, LDS atomic
        }
        if (lane == 0 && mingap < THETA) {
            unsigned int pos = atomicAdd(risk_cnt, 1u);
            if (pos < risk_cap) risk_list[pos] = (unsigned int)tok_g;
        }
    }
    atomicAdd(&pi_ws[lane], pi_acc);
    __syncthreads();
    if (t < 64) atomicAdd(&ce_ws[t], smem[4608 + t]);
}

// =====================================================================
// Pass B: fp64 recompute of risky tokens (exact ranking), overwrite
// idx/weight outputs. ~1-4% of tokens expected.
// =====================================================================
__global__ __launch_bounds__(256)
void gate_fixup(const float* __restrict__ hs, const float* __restrict__ wt,
                float* __restrict__ out, const unsigned int* __restrict__ risk_cnt,
                const unsigned int* __restrict__ risk_list, unsigned int risk_cap,
                int n_tokens) {
    __shared__ float  hrow[H];
    __shared__ double red[256];
    unsigned int cnt = *risk_cnt;
    if (cnt > risk_cap) cnt = risk_cap;
    const int t = threadIdx.x;

    for (unsigned int u = blockIdx.x; u < cnt; u += gridDim.x) {
        const int tok = (int)risk_list[u];
        for (int i = t; i < H; i += 256) hrow[i] = hs[(size_t)tok * H + i];
        __syncthreads();

        const int e = t >> 2, sl = t & 3;         // 4 threads per expert
        double acc = 0.0;
        const float4* wrow = (const float4*)(wt + (size_t)e * H) + sl * 64;
        const float*  hseg = hrow + sl * 256;
        #pragma unroll 4
        for (int k4 = 0; k4 < 64; ++k4) {
            float4 wv = wrow[k4];
            acc = fma((double)wv.x, (double)hseg[k4 * 4 + 0], acc);
            acc = fma((double)wv.y, (double)hseg[k4 * 4 + 1], acc);
            acc = fma((double)wv.z, (double)hseg[k4 * 4 + 2], acc);
            acc = fma((double)wv.w, (double)hseg[k4 * 4 + 3], acc);
        }
        red[t] = acc;
        __syncthreads();

        if (t < 64) {                             // wave 0: fp64 softmax + top-8
            const int lane = t;
            double lg = red[t * 4] + red[t * 4 + 1] + red[t * 4 + 2] + red[t * 4 + 3];
            double m = lg;
            #pragma unroll
            for (int off = 32; off > 0; off >>= 1) {
                double o = __shfl_xor(m, off, 64);
                m = (o > m) ? o : m;
            }
            const double p = exp(lg - m);
            double v = lg, psum = 0.0, mypv = 0.0;
            int myidx = 0;
            for (int r = 0; r < 8; ++r) {
                double bv = v; int bi = lane;
                #pragma unroll
                for (int off = 32; off > 0; off >>= 1) {
                    double ov = __shfl_xor(bv, off, 64);
                    int    oi = __shfl_xor(bi, off, 64);
                    if (ov > bv || (ov == bv && oi < bi)) { bv = ov; bi = oi; }
                }
                double pw = __shfl(p, bi, 64);
                psum += pw;
                if (lane == r) { myidx = bi; mypv = pw; }
                if (lane == bi) v = -1e300;
            }
            const double wsum = psum + 1e-20;
            if (lane < 8) {
                out[(size_t)tok * 8 + lane] = (float)myidx;
                out[(size_t)n_tokens * 8 + (size_t)tok * 8 + lane] = (float)(mypv / wsum);
            }
        }
        __syncthreads();
    }
}

// =====================================================================
// Pass C: finalize aux loss from pi/ce partials.
// =====================================================================
__global__ void gate_aux(const float* __restrict__ pi_ws, const float* __restrict__ ce_ws,
                         float* __restrict__ out, int n_tokens) {
    const int lane = threadIdx.x;                 // 64 threads
    double pi = (double)pi_ws[lane] / (double)n_tokens;
    double ce = (double)ce_ws[lane] / ((double)n_tokens * 8.0);
    double term = pi * ce * 64.0;
    #pragma unroll
    for (int off = 32; off > 0; off >>= 1) term += __shfl_xor(term, off, 64);
    if (lane == 0) out[(size_t)n_tokens * 16] = (float)(term * 0.01);
}

extern "C" void kernel_launch(void* const* d_in, const int* in_sizes, int n_in,
                              void* d_out, int out_size, void* d_ws, size_t ws_size,
                              hipStream_t stream) {
    const float* hs = (const float*)d_in[0];
    const float* wt = (const float*)d_in[1];
    float* out = (float*)d_out;
    const int n_tokens = in_sizes[0] / H;         // 32768

    // ws layout: pi[64]f @0, ce[64]f @256, risk_cnt u32 @512, risk_list @1024
    float* pi_ws = (float*)d_ws;
    float* ce_ws = (float*)((char*)d_ws + 256);
    unsigned int* risk_cnt  = (unsigned int*)((char*)d_ws + 512);
    unsigned int* risk_list = (unsigned int*)((char*)d_ws + 1024);
    unsigned int risk_cap = (unsigned int)((ws_size > 1024 ? (ws_size - 1024) : 0) / 4);
    if (risk_cap > (unsigned int)n_tokens) risk_cap = (unsigned int)n_tokens;

    size_t zbytes = ws_size < 1024 ? ws_size : 1024;
    hipMemsetAsync(d_ws, 0, zbytes, stream);

    gate_main<<<n_tokens / BT, 256, 0, stream>>>(hs, wt, out, pi_ws, ce_ws,
                                                 risk_cnt, risk_list, risk_cap, n_tokens);
    gate_fixup<<<128, 256, 0, stream>>>(hs, wt, out, risk_cnt, risk_list, risk_cap, n_tokens);
    gate_aux<<<1, 64, 0, stream>>>(pi_ws, ce_ws, out, n_tokens);
}

// Round 2
// 270.320 us; speedup vs baseline: 1.3415x; 1.3415x over previous
//
#include <hip/hip_runtime.h>

#define H 1024
#define E 64
#define BT 64
#define THETA 1e-4f    // relative p-gap risk threshold (~= logit gap)

// =====================================================================
// Pass A: fp32 logits GEMM (64 tokens x 64 experts per block) ->
// softmax(p) in LDS -> thread-per-token insertion top-9 (one wave,
// chosen by blockIdx&3 for SIMD balance) + concurrent pi partials on
// the other 3 waves. Aux partials via LDS hist + one atomic per expert.
// =====================================================================
__global__ __launch_bounds__(256, 2)
void gate_main(const float* __restrict__ hs, const float* __restrict__ wt,
               float* __restrict__ out, float* __restrict__ pi_ws,
               float* __restrict__ ce_ws, unsigned int* __restrict__ risk_cnt,
               unsigned int* __restrict__ risk_list, unsigned int risk_cap,
               int n_tokens) {
    __shared__ float smem[16384];                 // 64 KB GEMM stage; reused after
    float4* h4 = (float4*)smem;                   // [64 rows][32 float4]
    float4* w4 = (float4*)(smem + 8192);          // [64 rows][32 float4]
    float4* S4 = (float4*)smem;                   // [64][17] float4 (row stride 68 f)
    float*  S  = smem;
    float*  recip = smem + 4352;                  // [64] 1/full_softmax_sum
    float*  hist  = smem + 4416;                  // [64] expert counts
    float*  pi3   = smem + 4480;                  // [192] pi partials (3 thirds)

    const int t = threadIdx.x;
    const int wave = t >> 6, lane = t & 63;
    const int tok_base = blockIdx.x * BT;
    const int tgi = t & 15;                       // token group (4 tokens)
    const int eg  = t >> 4;                       // expert group (4 experts)
    const int swz_h = tgi & 7;
    const int swz_w = eg & 7;

    const float4* hs4 = (const float4*)hs;
    const float4* wt4 = (const float4*)wt;

    float acc[4][4];
    #pragma unroll
    for (int j = 0; j < 4; ++j)
        #pragma unroll
        for (int i = 0; i < 4; ++i) acc[j][i] = 0.f;

    for (int c = 0; c < 8; ++c) {                 // 8 K-chunks of 128
        #pragma unroll
        for (int i = 0; i < 8; ++i) {
            int row = i * 8 + (t >> 5);
            int kq  = t & 31;
            int sw  = (row >> 2) & 7;
            h4[row * 32 + (kq ^ sw)] = hs4[(size_t)(tok_base + row) * 256 + c * 32 + kq];
            w4[row * 32 + (kq ^ sw)] = wt4[(size_t)row * 256 + c * 32 + kq];
        }
        __syncthreads();
        #pragma unroll 8
        for (int kq = 0; kq < 32; ++kq) {
            const int ph = kq ^ swz_h;
            const int pw = kq ^ swz_w;
            float4 hv[4], wv[4];
            #pragma unroll
            for (int j = 0; j < 4; ++j) hv[j] = h4[(tgi * 4 + j) * 32 + ph];
            #pragma unroll
            for (int i = 0; i < 4; ++i) wv[i] = w4[(eg * 4 + i) * 32 + pw];
            #pragma unroll
            for (int j = 0; j < 4; ++j)
                #pragma unroll
                for (int i = 0; i < 4; ++i) {
                    acc[j][i] = fmaf(hv[j].x, wv[i].x, acc[j][i]);
                    acc[j][i] = fmaf(hv[j].y, wv[i].y, acc[j][i]);
                    acc[j][i] = fmaf(hv[j].z, wv[i].z, acc[j][i]);
                    acc[j][i] = fmaf(hv[j].w, wv[i].w, acc[j][i]);
                }
        }
        __syncthreads();
    }

    // ---- write logits to S[64][68] (float4 stores), zero hist ----
    #pragma unroll
    for (int j = 0; j < 4; ++j)
        S4[(tgi * 4 + j) * 17 + eg] = make_float4(acc[j][0], acc[j][1], acc[j][2], acc[j][3]);
    if (t < 64) hist[t] = 0.f;
    __syncthreads();

    // ---- phase P: p = exp(l - m) in-place, 4 threads per token ----
    {
        const int tok = t >> 2, q = t & 3;
        float4 v[4];
        #pragma unroll
        for (int c = 0; c < 4; ++c) v[c] = S4[tok * 17 + q * 4 + c];
        float m = v[0].x;
        #pragma unroll
        for (int c = 0; c < 4; ++c) {
            m = fmaxf(m, fmaxf(fmaxf(v[c].x, v[c].y), fmaxf(v[c].z, v[c].w)));
        }
        m = fmaxf(m, __shfl_xor(m, 1, 64));
        m = fmaxf(m, __shfl_xor(m, 2, 64));
        float lsum = 0.f;
        #pragma unroll
        for (int c = 0; c < 4; ++c) {
            v[c].x = __expf(v[c].x - m); v[c].y = __expf(v[c].y - m);
            v[c].z = __expf(v[c].z - m); v[c].w = __expf(v[c].w - m);
            lsum += (v[c].x + v[c].y) + (v[c].z + v[c].w);
        }
        #pragma unroll
        for (int c = 0; c < 4; ++c) S4[tok * 17 + q * 4 + c] = v[c];
        lsum += __shfl_xor(lsum, 1, 64);
        lsum += __shfl_xor(lsum, 2, 64);
        if (q == 0) recip[tok] = 1.0f / lsum;
    }
    __syncthreads();

    // ---- phase SEL (one wave, thread-per-token) + pi (other waves) ----
    const int selw = blockIdx.x & 3;
    if (wave == selw) {
        const int tok = lane;
        const int tok_g = tok_base + tok;
        float val[9]; int idx[9];
        #pragma unroll
        for (int r = 0; r < 9; ++r) { val[r] = -1.f; idx[r] = 0; }
        #pragma unroll
        for (int c = 0; c < 16; ++c) {
            float4 v = S4[tok * 17 + c];
            float e4[4] = {v.x, v.y, v.z, v.w};
            #pragma unroll
            for (int u = 0; u < 4; ++u) {
                float cv = e4[u]; int ci = c * 4 + u;
                #pragma unroll
                for (int r = 0; r < 9; ++r) {
                    const bool g = cv > val[r];        // strict: stream order = stable ties
                    const float tv = val[r]; const int ti = idx[r];
                    val[r] = g ? cv : tv;  idx[r] = g ? ci : ti;
                    cv = g ? tv : cv;      ci = g ? ti : ci;
                }
            }
        }
        const float s8 = ((val[0] + val[1]) + (val[2] + val[3]))
                       + ((val[4] + val[5]) + (val[6] + val[7]));
        const float wsum = s8 + 1e-20f;
        float4* out4 = (float4*)out;
        out4[(size_t)tok_g * 2]     = make_float4((float)idx[0], (float)idx[1], (float)idx[2], (float)idx[3]);
        out4[(size_t)tok_g * 2 + 1] = make_float4((float)idx[4], (float)idx[5], (float)idx[6], (float)idx[7]);
        const size_t wb = (size_t)n_tokens * 2;
        out4[wb + (size_t)tok_g * 2]     = make_float4(val[0] / wsum, val[1] / wsum, val[2] / wsum, val[3] / wsum);
        out4[wb + (size_t)tok_g * 2 + 1] = make_float4(val[4] / wsum, val[5] / wsum, val[6] / wsum, val[7] / wsum);
        #pragma unroll
        for (int r = 0; r < 8; ++r) atomicAdd(&hist[idx[r]], 1.0f);
        float ming = 1e30f;
        #pragma unroll
        for (int r = 0; r < 8; ++r)
            ming = fminf(ming, (val[r] - val[r + 1]) / fmaxf(val[r], 1e-30f));
        if (ming < THETA) {
            unsigned int pos = atomicAdd(risk_cnt, 1u);
            if (pos < risk_cap) risk_list[pos] = (unsigned int)tok_g;
        }
    } else {
        const int third = ((wave - selw) & 3) - 1;        // 0..2
        const int e = lane;
        const int t0 = third * 21;
        const int t1 = (third == 2) ? 64 : (t0 + 21);
        float part = 0.f;
        for (int tok = t0; tok < t1; ++tok)
            part = fmaf(S[tok * 68 + e], recip[tok], part);
        pi3[third * 64 + e] = part;
    }
    __syncthreads();
    if (t < 64)       atomicAdd(&pi_ws[t], pi3[t] + pi3[64 + t] + pi3[128 + t]);
    else if (t < 128) atomicAdd(&ce_ws[t - 64], hist[t - 64]);
}

// =====================================================================
// Pass B: fp64 recompute of risky tokens (exact ranking). Block per
// token (grid-stride), coalesced w reads, identical select semantics
// to round 1 (which passed).
// =====================================================================
__global__ __launch_bounds__(256)
void gate_fixup(const float* __restrict__ hs, const float* __restrict__ wt,
                float* __restrict__ out, const unsigned int* __restrict__ risk_cnt,
                const unsigned int* __restrict__ risk_list, unsigned int risk_cap,
                int n_tokens) {
    __shared__ float hrow[H];
    __shared__ double red[256];
    unsigned int cnt = *risk_cnt;
    if (cnt > risk_cap) cnt = risk_cap;
    const int t = threadIdx.x;

    for (unsigned int u = blockIdx.x; u < cnt; u += gridDim.x) {
        const int tok = (int)risk_list[u];
        ((float4*)hrow)[t] = ((const float4*)(hs + (size_t)tok * H))[t];
        __syncthreads();

        const int e = t >> 2, sl = t & 3;         // 4 threads per expert, interleaved f4
        const float4* wp = (const float4*)wt + (size_t)e * 256;
        const float4* hp = (const float4*)hrow;
        double acc = 0.0;
        #pragma unroll 8
        for (int k4 = 0; k4 < 64; ++k4) {
            float4 wv = wp[k4 * 4 + sl];
            float4 hv = hp[k4 * 4 + sl];
            acc = fma((double)wv.x, (double)hv.x, acc);
            acc = fma((double)wv.y, (double)hv.y, acc);
            acc = fma((double)wv.z, (double)hv.z, acc);
            acc = fma((double)wv.w, (double)hv.w, acc);
        }
        red[t] = acc;
        __syncthreads();

        if (t < 64) {
            const int lane = t;
            double lg = red[t * 4] + red[t * 4 + 1] + red[t * 4 + 2] + red[t * 4 + 3];
            double m = lg;
            #pragma unroll
            for (int off = 32; off > 0; off >>= 1) {
                double o = __shfl_xor(m, off, 64);
                m = (o > m) ? o : m;
            }
            const double p = exp(lg - m);
            double v = lg, psum = 0.0, mypv = 0.0;
            int myidx = 0;
            for (int r = 0; r < 8; ++r) {
                double bv = v; int bi = lane;
                #pragma unroll
                for (int off = 32; off > 0; off >>= 1) {
                    double ov = __shfl_xor(bv, off, 64);
                    int    oi = __shfl_xor(bi, off, 64);
                    if (ov > bv || (ov == bv && oi < bi)) { bv = ov; bi = oi; }
                }
                double pw = __shfl(p, bi, 64);
                psum += pw;
                if (lane == r) { myidx = bi; mypv = pw; }
                if (lane == bi) v = -1e300;
            }
            const double wsum = psum + 1e-20;
            if (lane < 8) {
                out[(size_t)tok * 8 + lane] = (float)myidx;
                out[(size_t)n_tokens * 8 + (size_t)tok * 8 + lane] = (float)(mypv / wsum);
            }
        }
        __syncthreads();
    }
}

// =====================================================================
// Pass C: finalize aux loss.
// =====================================================================
__global__ void gate_aux(const float* __restrict__ pi_ws, const float* __restrict__ ce_ws,
                         float* __restrict__ out, int n_tokens) {
    const int lane = threadIdx.x;                 // 64 threads
    double pi = (double)pi_ws[lane] / (double)n_tokens;
    double ce = (double)ce_ws[lane] / ((double)n_tokens * 8.0);
    double term = pi * ce * 64.0;
    #pragma unroll
    for (int off = 32; off > 0; off >>= 1) term += __shfl_xor(term, off, 64);
    if (lane == 0) out[(size_t)n_tokens * 16] = (float)(term * 0.01);
}

extern "C" void kernel_launch(void* const* d_in, const int* in_sizes, int n_in,
                              void* d_out, int out_size, void* d_ws, size_t ws_size,
                              hipStream_t stream) {
    const float* hs = (const float*)d_in[0];
    const float* wt = (const float*)d_in[1];
    float* out = (float*)d_out;
    const int n_tokens = in_sizes[0] / H;         // 32768

    float* pi_ws = (float*)d_ws;
    float* ce_ws = (float*)((char*)d_ws + 256);
    unsigned int* risk_cnt  = (unsigned int*)((char*)d_ws + 512);
    unsigned int* risk_list = (unsigned int*)((char*)d_ws + 1024);
    unsigned int risk_cap = (unsigned int)((ws_size > 1024 ? (ws_size - 1024) : 0) / 4);
    if (risk_cap > (unsigned int)n_tokens) risk_cap = (unsigned int)n_tokens;

    size_t zbytes = ws_size < 1024 ? ws_size : 1024;
    hipMemsetAsync(d_ws, 0, zbytes, stream);

    gate_main<<<n_tokens / BT, 256, 0, stream>>>(hs, wt, out, pi_ws, ce_ws,
                                                 risk_cnt, risk_list, risk_cap, n_tokens);
    gate_fixup<<<256, 256, 0, stream>>>(hs, wt, out, risk_cnt, risk_list, risk_cap, n_tokens);
    gate_aux<<<1, 64, 0, stream>>>(pi_ws, ce_ws, out, n_tokens);
}

// Round 3
// 244.655 us; speedup vs baseline: 1.4822x; 1.1049x over previous
//
#include <hip/hip_runtime.h>

#define H 1024
#define E 64
#define BT 64
#define THETA 1e-4f    // relative p-gap risk threshold (~= logit gap)

typedef __attribute__((ext_vector_type(4))) float f4;
typedef __attribute__((ext_vector_type(2))) float f2;

// packed dual-fp32 FMA: acc.lo += a.lo*b.lo; acc.hi += a.hi*b.hi
__device__ __forceinline__ void pkfma(f2& acc, f2 a, f2 b) {
    asm("v_pk_fma_f32 %0, %1, %2, %0" : "+v"(acc) : "v"(a), "v"(b));
}

// async global->LDS, 16B per lane; LDS dest = wave-uniform base + lane*16
__device__ __forceinline__ void async16(const void* g, void* l) {
    __builtin_amdgcn_global_load_lds(
        (const __attribute__((address_space(1))) unsigned int*)g,
        (__attribute__((address_space(3))) unsigned int*)l,
        16, 0, 0);
}

// =====================================================================
// Pass A: 64 tokens x 64 experts per block, K-chunks of 64, double-
// buffered global_load_lds staging (source-side XOR swizzle), packed
// fp32 FMA inner loop (4 tok x 4 exp per thread), then softmax/top-8/
// pi/hist tail identical in structure to the round-2 version.
// LDS float map: buf0 h[0,4096) w[4096,8192) | buf1 h[8192,12288) w[12288,16384)
// tail (reuses buf0): S[64][68] @0, recip @4352, hist @4416, pi3 @4480
// =====================================================================
__global__ __launch_bounds__(256, 2)
void gate_main(const float* __restrict__ hs, const float* __restrict__ wt,
               float* __restrict__ out, float* __restrict__ pi_ws,
               float* __restrict__ ce_ws, unsigned int* __restrict__ risk_cnt,
               unsigned int* __restrict__ risk_list, unsigned int risk_cap,
               int n_tokens) {
    __shared__ float smem[16384];                 // 64 KB
    const int t = threadIdx.x;
    const int wave = t >> 6, lane = t & 63;
    const int tok_base = blockIdx.x * BT;
    const int tg = t >> 4;                        // 0..15, tokens tg*4..+3
    const int eg = t & 15;                        // 0..15, experts eg*4..+3

    f2 acc[4][4];
    #pragma unroll
    for (int j = 0; j < 4; ++j)
        #pragma unroll
        for (int i = 0; i < 4; ++i) acc[j][i] = (f2){0.f, 0.f};

    // ---- staging: chunk c (64 k) into buffer b; swizzled SOURCE so the
    // lane-contiguous LDS layout holds LDS[row][j] = global[row][j^((row>>2)&7)]
    auto stage = [&](int c, int b) {
        const int bb = b * 8192;
        #pragma unroll
        for (int q = 0; q < 4; ++q) {
            const int L = q * 256 + t;            // f4 linear index in [0,1024)
            const int row = L >> 4, j = L & 15;
            const int srcj = j ^ ((row >> 2) & 7);
            const float* gh = hs + (size_t)(tok_base + row) * H + c * 64 + srcj * 4;
            async16(gh, smem + bb + (q * 256 + wave * 64) * 4);
            const float* gw = wt + (size_t)row * H + c * 64 + srcj * 4;
            async16(gw, smem + bb + 4096 + (q * 256 + wave * 64) * 4);
        }
    };

    stage(0, 0);
    const int swh = tg & 7, swe = eg & 7;
    for (int c = 0; c < 16; ++c) {
        __syncthreads();                          // drains vmcnt: stage(c) complete
        if (c < 15) stage(c + 1, (c + 1) & 1);
        const f4* hb = (const f4*)(smem + (c & 1) * 8192);
        const f4* wb = hb + 1024;
        #pragma unroll
        for (int kq = 0; kq < 16; ++kq) {
            f4 hv[4], wv[4];
            #pragma unroll
            for (int j = 0; j < 4; ++j) hv[j] = hb[(tg * 4 + j) * 16 + (kq ^ swh)];
            #pragma unroll
            for (int i = 0; i < 4; ++i) wv[i] = wb[(eg * 4 + i) * 16 + (kq ^ swe)];
            #pragma unroll
            for (int j = 0; j < 4; ++j)
                #pragma unroll
                for (int i = 0; i < 4; ++i) {
                    pkfma(acc[j][i], __builtin_shufflevector(hv[j], hv[j], 0, 1),
                                     __builtin_shufflevector(wv[i], wv[i], 0, 1));
                    pkfma(acc[j][i], __builtin_shufflevector(hv[j], hv[j], 2, 3),
                                     __builtin_shufflevector(wv[i], wv[i], 2, 3));
                }
        }
    }
    __syncthreads();

    // ---- fold packed halves, write logits S[64][68] ----
    f4* S4 = (f4*)smem;
    float* S = smem;
    float* recip = smem + 4352;
    float* hist  = smem + 4416;
    float* pi3   = smem + 4480;
    #pragma unroll
    for (int j = 0; j < 4; ++j) {
        f4 v;
        v.x = acc[j][0].x + acc[j][0].y;
        v.y = acc[j][1].x + acc[j][1].y;
        v.z = acc[j][2].x + acc[j][2].y;
        v.w = acc[j][3].x + acc[j][3].y;
        S4[(tg * 4 + j) * 17 + eg] = v;
    }
    if (t < 64) hist[t] = 0.f;
    __syncthreads();

    // ---- p = exp(l - m) in-place, 4 threads per token ----
    {
        const int tok = t >> 2, q = t & 3;
        f4 v[4];
        #pragma unroll
        for (int c = 0; c < 4; ++c) v[c] = S4[tok * 17 + q * 4 + c];
        float m = v[0].x;
        #pragma unroll
        for (int c = 0; c < 4; ++c)
            m = fmaxf(m, fmaxf(fmaxf(v[c].x, v[c].y), fmaxf(v[c].z, v[c].w)));
        m = fmaxf(m, __shfl_xor(m, 1, 64));
        m = fmaxf(m, __shfl_xor(m, 2, 64));
        float lsum = 0.f;
        #pragma unroll
        for (int c = 0; c < 4; ++c) {
            v[c].x = __expf(v[c].x - m); v[c].y = __expf(v[c].y - m);
            v[c].z = __expf(v[c].z - m); v[c].w = __expf(v[c].w - m);
            lsum += (v[c].x + v[c].y) + (v[c].z + v[c].w);
        }
        #pragma unroll
        for (int c = 0; c < 4; ++c) S4[tok * 17 + q * 4 + c] = v[c];
        lsum += __shfl_xor(lsum, 1, 64);
        lsum += __shfl_xor(lsum, 2, 64);
        if (q == 0) recip[tok] = 1.0f / lsum;
    }
    __syncthreads();

    // ---- SEL (one wave, thread-per-token) + pi partials (other waves) ----
    const int selw = blockIdx.x & 3;
    if (wave == selw) {
        const int tok = lane;
        const int tok_g = tok_base + tok;
        float val[9]; int idx[9];
        #pragma unroll
        for (int r = 0; r < 9; ++r) { val[r] = -1.f; idx[r] = 0; }
        #pragma unroll
        for (int c = 0; c < 16; ++c) {
            f4 v = S4[tok * 17 + c];
            float e4[4] = {v.x, v.y, v.z, v.w};
            #pragma unroll
            for (int u = 0; u < 4; ++u) {
                float cv = e4[u]; int ci = c * 4 + u;
                #pragma unroll
                for (int r = 0; r < 9; ++r) {
                    const bool g = cv > val[r];    // strict: stream order = stable ties
                    const float tv = val[r]; const int ti = idx[r];
                    val[r] = g ? cv : tv;  idx[r] = g ? ci : ti;
                    cv = g ? tv : cv;      ci = g ? ti : ci;
                }
            }
        }
        const float s8 = ((val[0] + val[1]) + (val[2] + val[3]))
                       + ((val[4] + val[5]) + (val[6] + val[7]));
        const float wsum = s8 + 1e-20f;
        f4* out4 = (f4*)out;
        f4 o;
        o.x = (float)idx[0]; o.y = (float)idx[1]; o.z = (float)idx[2]; o.w = (float)idx[3];
        out4[(size_t)tok_g * 2] = o;
        o.x = (float)idx[4]; o.y = (float)idx[5]; o.z = (float)idx[6]; o.w = (float)idx[7];
        out4[(size_t)tok_g * 2 + 1] = o;
        const size_t wb = (size_t)n_tokens * 2;
        o.x = val[0] / wsum; o.y = val[1] / wsum; o.z = val[2] / wsum; o.w = val[3] / wsum;
        out4[wb + (size_t)tok_g * 2] = o;
        o.x = val[4] / wsum; o.y = val[5] / wsum; o.z = val[6] / wsum; o.w = val[7] / wsum;
        out4[wb + (size_t)tok_g * 2 + 1] = o;
        #pragma unroll
        for (int r = 0; r < 8; ++r) atomicAdd(&hist[idx[r]], 1.0f);
        float ming = 1e30f;
        #pragma unroll
        for (int r = 0; r < 8; ++r)
            ming = fminf(ming, (val[r] - val[r + 1]) / fmaxf(val[r], 1e-30f));
        if (ming < THETA) {
            unsigned int pos = atomicAdd(risk_cnt, 1u);
            if (pos < risk_cap) risk_list[pos] = (unsigned int)tok_g;
        }
    } else {
        const int third = ((wave - selw) & 3) - 1;        // 0..2
        const int e = lane;
        const int t0 = third * 21;
        const int t1 = (third == 2) ? 64 : (t0 + 21);
        float part = 0.f;
        for (int tok = t0; tok < t1; ++tok)
            part = fmaf(S[tok * 68 + e], recip[tok], part);
        pi3[third * 64 + e] = part;
    }
    __syncthreads();
    if (t < 64)       atomicAdd(&pi_ws[t], pi3[t] + pi3[64 + t] + pi3[128 + t]);
    else if (t < 128) atomicAdd(&ce_ws[t - 64], hist[t - 64]);
}

// =====================================================================
// Pass B: fp64 recompute of risky tokens (exact ranking).
// =====================================================================
__global__ __launch_bounds__(256)
void gate_fixup(const float* __restrict__ hs, const float* __restrict__ wt,
                float* __restrict__ out, const unsigned int* __restrict__ risk_cnt,
                const unsigned int* __restrict__ risk_list, unsigned int risk_cap,
                int n_tokens) {
    __shared__ float hrow[H];
    __shared__ double red[256];
    unsigned int cnt = *risk_cnt;
    if (cnt > risk_cap) cnt = risk_cap;
    const int t = threadIdx.x;

    for (unsigned int u = blockIdx.x; u < cnt; u += gridDim.x) {
        const int tok = (int)risk_list[u];
        ((float4*)hrow)[t] = ((const float4*)(hs + (size_t)tok * H))[t];
        __syncthreads();

        const int e = t >> 2, sl = t & 3;
        const float4* wp = (const float4*)wt + (size_t)e * 256;
        const float4* hp = (const float4*)hrow;
        double acc = 0.0;
        #pragma unroll 8
        for (int k4 = 0; k4 < 64; ++k4) {
            float4 wv = wp[k4 * 4 + sl];
            float4 hv = hp[k4 * 4 + sl];
            acc = fma((double)wv.x, (double)hv.x, acc);
            acc = fma((double)wv.y, (double)hv.y, acc);
            acc = fma((double)wv.z, (double)hv.z, acc);
            acc = fma((double)wv.w, (double)hv.w, acc);
        }
        red[t] = acc;
        __syncthreads();

        if (t < 64) {
            const int lane = t;
            double lg = red[t * 4] + red[t * 4 + 1] + red[t * 4 + 2] + red[t * 4 + 3];
            double m = lg;
            #pragma unroll
            for (int off = 32; off > 0; off >>= 1) {
                double o = __shfl_xor(m, off, 64);
                m = (o > m) ? o : m;
            }
            const double p = exp(lg - m);
            double v = lg, psum = 0.0, mypv = 0.0;
            int myidx = 0;
            for (int r = 0; r < 8; ++r) {
                double bv = v; int bi = lane;
                #pragma unroll
                for (int off = 32; off > 0; off >>= 1) {
                    double ov = __shfl_xor(bv, off, 64);
                    int    oi = __shfl_xor(bi, off, 64);
                    if (ov > bv || (ov == bv && oi < bi)) { bv = ov; bi = oi; }
                }
                double pw = __shfl(p, bi, 64);
                psum += pw;
                if (lane == r) { myidx = bi; mypv = pw; }
                if (lane == bi) v = -1e300;
            }
            const double wsum = psum + 1e-20;
            if (lane < 8) {
                out[(size_t)tok * 8 + lane] = (float)myidx;
                out[(size_t)n_tokens * 8 + (size_t)tok * 8 + lane] = (float)(mypv / wsum);
            }
        }
        __syncthreads();
    }
}

// =====================================================================
// Pass C: finalize aux loss.
// =====================================================================
__global__ void gate_aux(const float* __restrict__ pi_ws, const float* __restrict__ ce_ws,
                         float* __restrict__ out, int n_tokens) {
    const int lane = threadIdx.x;                 // 64 threads
    double pi = (double)pi_ws[lane] / (double)n_tokens;
    double ce = (double)ce_ws[lane] / ((double)n_tokens * 8.0);
    double term = pi * ce * 64.0;
    #pragma unroll
    for (int off = 32; off > 0; off >>= 1) term += __shfl_xor(term, off, 64);
    if (lane == 0) out[(size_t)n_tokens * 16] = (float)(term * 0.01);
}

extern "C" void kernel_launch(void* const* d_in, const int* in_sizes, int n_in,
                              void* d_out, int out_size, void* d_ws, size_t ws_size,
                              hipStream_t stream) {
    const float* hs = (const float*)d_in[0];
    const float* wt = (const float*)d_in[1];
    float* out = (float*)d_out;
    const int n_tokens = in_sizes[0] / H;         // 32768

    float* pi_ws = (float*)d_ws;
    float* ce_ws = (float*)((char*)d_ws + 256);
    unsigned int* risk_cnt  = (unsigned int*)((char*)d_ws + 512);
    unsigned int* risk_list = (unsigned int*)((char*)d_ws + 1024);
    unsigned int risk_cap = (unsigned int)((ws_size > 1024 ? (ws_size - 1024) : 0) / 4);
    if (risk_cap > (unsigned int)n_tokens) risk_cap = (unsigned int)n_tokens;

    size_t zbytes = ws_size < 1024 ? ws_size : 1024;
    hipMemsetAsync(d_ws, 0, zbytes, stream);

    gate_main<<<n_tokens / BT, 256, 0, stream>>>(hs, wt, out, pi_ws, ce_ws,
                                                 risk_cnt, risk_list, risk_cap, n_tokens);
    gate_fixup<<<256, 256, 0, stream>>>(hs, wt, out, risk_cnt, risk_list, risk_cap, n_tokens);
    gate_aux<<<1, 64, 0, stream>>>(pi_ws, ce_ws, out, n_tokens);
}